// Round 2
// baseline (6999.178 us; speedup 1.0000x reference)
//
#include <hip/hip_runtime.h>
#include <math.h>

// Problem dims (fixed by reference)
static constexpr int Bb  = 4;
static constexpr int Ll  = 4096;
static constexpr int Dd  = 1024;
static constexpr int DFF = 4096;
static constexpr int Mm  = Bb * Ll;     // 16384 rows
static constexpr int CH  = 64;          // number of scan chunks
static constexpr int CS  = Ll / CH;     // 64 steps per chunk
static constexpr float EPS = 1e-6f;

__device__ __forceinline__ float sigmoidf_(float v) { return 1.0f / (1.0f + __expf(-v)); }

// ---------------------------------------------------------------------------
// RMSNorm: one block per row, 256 threads, D=1024 -> 1 float4 per thread
// ---------------------------------------------------------------------------
__global__ __launch_bounds__(256) void rmsnorm_kernel(
    const float* __restrict__ x, const float* __restrict__ w,
    float* __restrict__ o)
{
    int row = blockIdx.x;
    int tid = threadIdx.x;
    const float4* xr = (const float4*)(x + (size_t)row * Dd);
    float4 v = xr[tid];
    float ss = v.x*v.x + v.y*v.y + v.z*v.z + v.w*v.w;
    #pragma unroll
    for (int off = 32; off > 0; off >>= 1) ss += __shfl_down(ss, off, 64);
    __shared__ float red[4];
    if ((tid & 63) == 0) red[tid >> 6] = ss;
    __syncthreads();
    float tot = red[0] + red[1] + red[2] + red[3];
    float scale = rsqrtf(tot * (1.0f / Dd) + EPS);
    const float4* wr = (const float4*)w;
    float4 wv = wr[tid];
    float4 ov;
    ov.x = v.x * scale * wv.x; ov.y = v.y * scale * wv.y;
    ov.z = v.z * scale * wv.z; ov.w = v.w * scale * wv.w;
    ((float4*)(o + (size_t)row * Dd))[tid] = ov;
}

// ---------------------------------------------------------------------------
// fp32 tiled GEMM: C = sigmoid(A[M,K] @ W[K,N] + bias)
// 64x64 tile, BK=16, 256 threads, 4x4 micro-tile
// ---------------------------------------------------------------------------
#define BT 64
#define BK 16

__global__ __launch_bounds__(256) void gemm_sigmoid(
    const float* __restrict__ A, const float* __restrict__ W,
    const float* __restrict__ bias, float* __restrict__ C,
    int M, int N, int K)
{
    __shared__ float As[BK][BT + 4];
    __shared__ float Bs[BK][BT];
    int tid = threadIdx.x;
    int tx = tid & 15, ty = tid >> 4;
    int m0 = blockIdx.y * BT, n0 = blockIdx.x * BT;

    int a_row = tid >> 2;            // 0..63
    int a_k4  = (tid & 3) * 4;       // 0,4,8,12
    int b_row = tid >> 4;            // 0..15
    int b_n4  = (tid & 15) * 4;      // 0..60

    float acc[4][4] = {};

    for (int k0 = 0; k0 < K; k0 += BK) {
        float4 av = *(const float4*)&A[(size_t)(m0 + a_row) * K + k0 + a_k4];
        float4 bv = *(const float4*)&W[(size_t)(k0 + b_row) * N + n0 + b_n4];
        As[a_k4 + 0][a_row] = av.x;
        As[a_k4 + 1][a_row] = av.y;
        As[a_k4 + 2][a_row] = av.z;
        As[a_k4 + 3][a_row] = av.w;
        *(float4*)&Bs[b_row][b_n4] = bv;
        __syncthreads();
        #pragma unroll
        for (int kk = 0; kk < BK; ++kk) {
            float4 a4 = *(const float4*)&As[kk][ty * 4];
            float4 b4 = *(const float4*)&Bs[kk][tx * 4];
            float a[4] = {a4.x, a4.y, a4.z, a4.w};
            float b[4] = {b4.x, b4.y, b4.z, b4.w};
            #pragma unroll
            for (int i = 0; i < 4; ++i)
                #pragma unroll
                for (int j = 0; j < 4; ++j)
                    acc[i][j] += a[i] * b[j];
        }
        __syncthreads();
    }

    float4 bias4 = *(const float4*)&bias[n0 + tx * 4];
    float bb[4] = {bias4.x, bias4.y, bias4.z, bias4.w};
    #pragma unroll
    for (int i = 0; i < 4; ++i) {
        int r = m0 + ty * 4 + i;
        float4 out;
        float* op = (float*)&out;
        #pragma unroll
        for (int j = 0; j < 4; ++j)
            op[j] = sigmoidf_(acc[i][j] + bb[j]);
        *(float4*)&C[(size_t)r * N + n0 + tx * 4] = out;
    }
}

// ---------------------------------------------------------------------------
// Dual GEMM with fused combine:
//   mode 0: C = tanh(A@W1+b1) * sigmoid(A@W2+b2)   (QuasiLSTM input gate)
//   mode 1: C = (A@W1+b1) * silu(A@W2+b2)          (SwiGLU)
// W pointers may be column-offset; ldW = full row stride of W; ldC = C stride.
// Grid covers Ncols columns of C.
// ---------------------------------------------------------------------------
__global__ __launch_bounds__(256) void gemm_dual(
    const float* __restrict__ A, const float* __restrict__ W1,
    const float* __restrict__ b1, const float* __restrict__ W2,
    const float* __restrict__ b2, float* __restrict__ C,
    int M, int K, int ldW, int ldC, int mode)
{
    __shared__ float As[BK][BT + 4];
    __shared__ float B1s[BK][BT];
    __shared__ float B2s[BK][BT];
    int tid = threadIdx.x;
    int tx = tid & 15, ty = tid >> 4;
    int m0 = blockIdx.y * BT, n0 = blockIdx.x * BT;

    int a_row = tid >> 2;
    int a_k4  = (tid & 3) * 4;
    int b_row = tid >> 4;
    int b_n4  = (tid & 15) * 4;

    float acc1[4][4] = {};
    float acc2[4][4] = {};

    for (int k0 = 0; k0 < K; k0 += BK) {
        float4 av  = *(const float4*)&A[(size_t)(m0 + a_row) * K + k0 + a_k4];
        float4 bv1 = *(const float4*)&W1[(size_t)(k0 + b_row) * ldW + n0 + b_n4];
        float4 bv2 = *(const float4*)&W2[(size_t)(k0 + b_row) * ldW + n0 + b_n4];
        As[a_k4 + 0][a_row] = av.x;
        As[a_k4 + 1][a_row] = av.y;
        As[a_k4 + 2][a_row] = av.z;
        As[a_k4 + 3][a_row] = av.w;
        *(float4*)&B1s[b_row][b_n4] = bv1;
        *(float4*)&B2s[b_row][b_n4] = bv2;
        __syncthreads();
        #pragma unroll
        for (int kk = 0; kk < BK; ++kk) {
            float4 a4 = *(const float4*)&As[kk][ty * 4];
            float4 c4 = *(const float4*)&B1s[kk][tx * 4];
            float4 d4 = *(const float4*)&B2s[kk][tx * 4];
            float a[4] = {a4.x, a4.y, a4.z, a4.w};
            float b[4] = {c4.x, c4.y, c4.z, c4.w};
            float c[4] = {d4.x, d4.y, d4.z, d4.w};
            #pragma unroll
            for (int i = 0; i < 4; ++i)
                #pragma unroll
                for (int j = 0; j < 4; ++j) {
                    acc1[i][j] += a[i] * b[j];
                    acc2[i][j] += a[i] * c[j];
                }
        }
        __syncthreads();
    }

    float4 b14 = *(const float4*)&b1[n0 + tx * 4];
    float4 b24 = *(const float4*)&b2[n0 + tx * 4];
    float bb1[4] = {b14.x, b14.y, b14.z, b14.w};
    float bb2[4] = {b24.x, b24.y, b24.z, b24.w};
    #pragma unroll
    for (int i = 0; i < 4; ++i) {
        int r = m0 + ty * 4 + i;
        float4 out;
        float* op = (float*)&out;
        #pragma unroll
        for (int j = 0; j < 4; ++j) {
            float z1 = acc1[i][j] + bb1[j];
            float z2 = acc2[i][j] + bb2[j];
            if (mode == 0) op[j] = tanhf(z1) * sigmoidf_(z2);
            else           op[j] = z1 * z2 * sigmoidf_(z2);
        }
        *(float4*)&C[(size_t)r * ldC + n0 + tx * 4] = out;
    }
}

// ---------------------------------------------------------------------------
// Residual GEMM: C = A[M,K]@W[K,N] + (addBias ? bias : 0) + R
// R may alias C (elementwise read-then-write by the owning thread).
// ---------------------------------------------------------------------------
__global__ __launch_bounds__(256) void gemm_residual(
    const float* __restrict__ A, const float* __restrict__ W,
    const float* __restrict__ bias, const float* __restrict__ R,
    float* __restrict__ C, int M, int N, int K, int ldA, int addBias)
{
    __shared__ float As[BK][BT + 4];
    __shared__ float Bs[BK][BT];
    int tid = threadIdx.x;
    int tx = tid & 15, ty = tid >> 4;
    int m0 = blockIdx.y * BT, n0 = blockIdx.x * BT;

    int a_row = tid >> 2;
    int a_k4  = (tid & 3) * 4;
    int b_row = tid >> 4;
    int b_n4  = (tid & 15) * 4;

    float acc[4][4] = {};

    for (int k0 = 0; k0 < K; k0 += BK) {
        float4 av = *(const float4*)&A[(size_t)(m0 + a_row) * ldA + k0 + a_k4];
        float4 bv = *(const float4*)&W[(size_t)(k0 + b_row) * N + n0 + b_n4];
        As[a_k4 + 0][a_row] = av.x;
        As[a_k4 + 1][a_row] = av.y;
        As[a_k4 + 2][a_row] = av.z;
        As[a_k4 + 3][a_row] = av.w;
        *(float4*)&Bs[b_row][b_n4] = bv;
        __syncthreads();
        #pragma unroll
        for (int kk = 0; kk < BK; ++kk) {
            float4 a4 = *(const float4*)&As[kk][ty * 4];
            float4 b4 = *(const float4*)&Bs[kk][tx * 4];
            float a[4] = {a4.x, a4.y, a4.z, a4.w};
            float b[4] = {b4.x, b4.y, b4.z, b4.w};
            #pragma unroll
            for (int i = 0; i < 4; ++i)
                #pragma unroll
                for (int j = 0; j < 4; ++j)
                    acc[i][j] += a[i] * b[j];
        }
        __syncthreads();
    }

    float4 bias4 = *(const float4*)&bias[n0 + tx * 4];
    float bb[4] = {bias4.x, bias4.y, bias4.z, bias4.w};
    #pragma unroll
    for (int i = 0; i < 4; ++i) {
        int r = m0 + ty * 4 + i;
        float4 rv = *(const float4*)&R[(size_t)r * N + n0 + tx * 4];
        float* rp = (float*)&rv;
        float4 out;
        float* op = (float*)&out;
        #pragma unroll
        for (int j = 0; j < 4; ++j)
            op[j] = acc[i][j] + (addBias ? bb[j] : 0.0f) + rp[j];
        *(float4*)&C[(size_t)r * N + n0 + tx * 4] = out;
    }
}

// ---------------------------------------------------------------------------
// Chunked linear-recurrence scan: h_t = a_t*h_{t-1} + b_t, h init = h0
// Ga = sigmoid(forget), Gb = tanh(input)*sigmoid(igate)
// ---------------------------------------------------------------------------
__global__ __launch_bounds__(256) void scan_pass1(
    const float* __restrict__ Ga, const float* __restrict__ Gb,
    float* __restrict__ P, float* __restrict__ Hend)
{
    int d = blockIdx.x * 256 + threadIdx.x;  // 0..1023
    int c = blockIdx.y;                      // chunk
    int b = blockIdx.z;                      // batch
    size_t base = ((size_t)b * Ll + (size_t)c * CS) * Dd + d;
    float p = 1.0f, h = 0.0f;
    for (int t = 0; t < CS; ++t) {
        size_t i = base + (size_t)t * Dd;
        float aa = Ga[i];
        float bb = Gb[i];
        p *= aa;
        h = aa * h + bb;
    }
    size_t o = ((size_t)b * CH + c) * Dd + d;
    P[o] = p;
    Hend[o] = h;
}

__global__ __launch_bounds__(256) void scan_pass2(
    const float* __restrict__ P, const float* __restrict__ Hend,
    const float* __restrict__ h0, float* __restrict__ Carry)
{
    int idx = blockIdx.x * 256 + threadIdx.x;  // B*D = 4096
    int b = idx / Dd, d = idx % Dd;
    float carry = h0[d];
    for (int c = 0; c < CH; ++c) {
        size_t o = ((size_t)b * CH + c) * Dd + d;
        Carry[o] = carry;
        carry = P[o] * carry + Hend[o];
    }
}

// Replays chunks with carry; writes pre-activation h. H may alias Ga
// (each element read once, then written, by the same thread).
__global__ __launch_bounds__(256) void scan_pass3(
    const float* __restrict__ Ga, const float* __restrict__ Gb,
    const float* __restrict__ Carry, float* __restrict__ H)
{
    int d = blockIdx.x * 256 + threadIdx.x;
    int c = blockIdx.y;
    int b = blockIdx.z;
    size_t base = ((size_t)b * Ll + (size_t)c * CS) * Dd + d;
    float h = Carry[((size_t)b * CH + c) * Dd + d];
    for (int t = 0; t < CS; ++t) {
        size_t i = base + (size_t)t * Dd;
        float aa = Ga[i];
        float bb = Gb[i];
        h = aa * h + bb;
        H[i] = h;
    }
}

// x1 = tanh(H) * Gog + x  (x1 may alias any operand elementwise)
__global__ __launch_bounds__(256) void ogate_combine(
    const float* __restrict__ H, const float* __restrict__ Gog,
    const float* __restrict__ x, float* __restrict__ x1, int n4)
{
    int i = blockIdx.x * 256 + threadIdx.x;
    if (i >= n4) return;
    float4 h4 = ((const float4*)H)[i];
    float4 g4 = ((const float4*)Gog)[i];
    float4 x4 = ((const float4*)x)[i];
    float4 o4;
    o4.x = tanhf(h4.x) * g4.x + x4.x;
    o4.y = tanhf(h4.y) * g4.y + x4.y;
    o4.z = tanhf(h4.z) * g4.z + x4.z;
    o4.w = tanhf(h4.w) * g4.w + x4.w;
    ((float4*)x1)[i] = o4;
}

// ---------------------------------------------------------------------------
// Launch.  Workspace peak: 3 x 64MB + 3MB = 195MB.
//   buf0: xn / xn2
//   buf1: Ga -> H (aliased by scan_pass3) -> hff chunk (low half)
//   buf2: Gb -> Gog -> hff chunk (high half)
//   smalls (ws+192MB): P, Hend, Carry (1MB each)
// d_out doubles as x1 then final out (elementwise-safe aliasing).
// ---------------------------------------------------------------------------
extern "C" void kernel_launch(void* const* d_in, const int* in_sizes, int n_in,
                              void* d_out, int out_size, void* d_ws, size_t ws_size,
                              hipStream_t stream)
{
    const float* x        = (const float*)d_in[0];
    const float* w_forget = (const float*)d_in[1];
    const float* b_forget = (const float*)d_in[2];
    const float* w_input  = (const float*)d_in[3];
    const float* b_input  = (const float*)d_in[4];
    const float* w_igate  = (const float*)d_in[5];
    const float* b_igate  = (const float*)d_in[6];
    const float* w_ogate  = (const float*)d_in[7];
    const float* b_ogate  = (const float*)d_in[8];
    const float* h0       = (const float*)d_in[9];
    const float* norm1_w  = (const float*)d_in[10];
    const float* norm2_w  = (const float*)d_in[11];
    const float* w_fc     = (const float*)d_in[12];
    const float* b_fc     = (const float*)d_in[13];
    const float* w_fc_act = (const float*)d_in[14];
    const float* b_fc_act = (const float*)d_in[15];
    const float* w_out    = (const float*)d_in[16];
    const float* b_out    = (const float*)d_in[17];
    float* out = (float*)d_out;   // doubles as x1

    char* ws = (char*)d_ws;
    const size_t big = (size_t)Mm * Dd * 4;          // 64 MiB
    float* buf0 = (float*)(ws + 0 * big);            // xn / xn2
    float* buf1 = (float*)(ws + 1 * big);            // Ga / H / hff-lo
    float* buf2 = (float*)(ws + 2 * big);            // Gb / Gog / hff-hi
    char*  tail = ws + 3 * big;
    const size_t small = (size_t)Bb * CH * Dd * 4;   // 1 MiB
    float* P     = (float*)(tail + 0 * small);
    float* Hend  = (float*)(tail + 1 * small);
    float* Carry = (float*)(tail + 2 * small);
    float* hff   = buf1;                             // [M, 2048] spans buf1+buf2

    // 1) xn = rmsnorm(x, norm1_w)
    rmsnorm_kernel<<<Mm, 256, 0, stream>>>(x, norm1_w, buf0);

    // 2) Ga = sigmoid(xn @ w_forget + b)
    dim3 gg(Dd / BT, Mm / BT);
    gemm_sigmoid<<<gg, 256, 0, stream>>>(buf0, w_forget, b_forget, buf1, Mm, Dd, Dd);

    // 3) Gb = tanh(xn @ w_input + b) * sigmoid(xn @ w_igate + b)
    gemm_dual<<<gg, 256, 0, stream>>>(buf0, w_input, b_input, w_igate, b_igate,
                                      buf2, Mm, Dd, Dd, Dd, /*mode=*/0);

    // 4) chunked scan -> H (pre-tanh), H aliases Ga in buf1
    dim3 sg(Dd / 256, CH, Bb);
    scan_pass1<<<sg, 256, 0, stream>>>(buf1, buf2, P, Hend);
    scan_pass2<<<(Bb * Dd) / 256, 256, 0, stream>>>(P, Hend, h0, Carry);
    scan_pass3<<<sg, 256, 0, stream>>>(buf1, buf2, Carry, buf1);

    // 5) Gog = sigmoid(xn @ w_ogate + b)  (buf2 free after pass3)
    gemm_sigmoid<<<gg, 256, 0, stream>>>(buf0, w_ogate, b_ogate, buf2, Mm, Dd, Dd);

    // 6) x1 = tanh(H) * Gog + x  -> d_out
    ogate_combine<<<(Mm * Dd / 4 + 255) / 256, 256, 0, stream>>>(
        buf1, buf2, x, out, Mm * Dd / 4);

    // 7) xn2 = rmsnorm(x1, norm2_w)
    rmsnorm_kernel<<<Mm, 256, 0, stream>>>(out, norm2_w, buf0);

    // 8+9) FFN in two 2048-column chunks with split-K accumulating out-GEMM
    dim3 gf(2048 / BT, Mm / BT);
    dim3 go(Dd / BT, Mm / BT);
    // chunk 0: hff = (xn2@w_fc[:, :2048]+b) * silu(xn2@w_fc_act[:, :2048]+b)
    gemm_dual<<<gf, 256, 0, stream>>>(buf0, w_fc, b_fc, w_fc_act, b_fc_act,
                                      hff, Mm, Dd, DFF, 2048, /*mode=*/1);
    // out = hff @ w_out[:2048] + b_out + x1
    gemm_residual<<<go, 256, 0, stream>>>(hff, w_out, b_out, out, out,
                                          Mm, Dd, 2048, 2048, /*addBias=*/1);
    // chunk 1
    gemm_dual<<<gf, 256, 0, stream>>>(buf0, w_fc + 2048, b_fc + 2048,
                                      w_fc_act + 2048, b_fc_act + 2048,
                                      hff, Mm, Dd, DFF, 2048, /*mode=*/1);
    gemm_residual<<<go, 256, 0, stream>>>(hff, w_out + (size_t)2048 * Dd, b_out,
                                          out, out, Mm, Dd, 2048, 2048, /*addBias=*/0);
}

// Round 3
// 1022.161 us; speedup vs baseline: 6.8474x; 6.8474x over previous
//
#include <hip/hip_runtime.h>
#include <math.h>
#include <stdint.h>

// Problem dims (fixed by reference)
static constexpr int Bb  = 4;
static constexpr int Ll  = 4096;
static constexpr int Dd  = 1024;
static constexpr int DFF = 4096;
static constexpr int Mm  = Bb * Ll;     // 16384 rows
static constexpr int CH  = 64;          // scan chunks
static constexpr int CS  = Ll / CH;     // 64 steps per chunk
static constexpr float EPS = 1e-6f;

typedef __attribute__((ext_vector_type(8))) short short8;     // 8 bf16 (4 VGPRs)
typedef __attribute__((ext_vector_type(4))) float floatx4;    // MFMA C/D
typedef __attribute__((ext_vector_type(4))) unsigned short us4;

__device__ __forceinline__ float sigmoidf_(float v) { return 1.0f / (1.0f + __expf(-v)); }
__device__ __forceinline__ ushort f2bf(float f) {
    union { float f; uint32_t u; } v; v.f = f;
    return (ushort)((v.u + 0x7FFFu + ((v.u >> 16) & 1u)) >> 16);   // RNE
}
__device__ __forceinline__ float bf2f(ushort h) {
    union { uint32_t u; float f; } v; v.u = (uint32_t)h << 16; return v.f;
}

// async global->LDS, 16 bytes per lane (wave-uniform base + lane*16 layout)
__device__ __forceinline__ void gload16(const ushort* g, ushort* l) {
    __builtin_amdgcn_global_load_lds(
        (const __attribute__((address_space(1))) uint32_t*)g,
        (__attribute__((address_space(3))) uint32_t*)l, 16, 0, 0);
}

// ---------------------------------------------------------------------------
// Stage a 128x32 bf16 tile into LDS, layout [m][32k] with 16B-chunk XOR
// swizzle: lds chunk (m*4 + slot) holds global k-block (slot ^ ((m>>1)&3)).
// Gives 2-way (free) LDS bank aliasing on ds_read_b128 fragment reads.
// ---------------------------------------------------------------------------
__device__ __forceinline__ void stage128x32(const ushort* __restrict__ src, int ld,
                                            int r0, int k0, ushort* lds, int tid)
{
    #pragma unroll
    for (int h = 0; h < 2; ++h) {
        int c  = tid + h * 256;            // chunk 0..511
        int m  = c >> 2;
        int kb = (c & 3) ^ ((m >> 1) & 3);
        gload16(src + (size_t)(r0 + m) * ld + k0 + kb * 8, lds + c * 8);
    }
}

// ---------------------------------------------------------------------------
// MFMA GEMM, single B: C_bf16 = sigmoid(A_bf16[M,K] @ Wt_bf16[N,K]^T + bias)
// 128x128 tile, 4 waves (2x2), each wave 64x64 = 4x4 of 16x16x32 MFMA, BK=32
// ---------------------------------------------------------------------------
__global__ __launch_bounds__(256, 2) void mfma_gemm_sigmoid(
    const ushort* __restrict__ A, const ushort* __restrict__ Wt,
    const float* __restrict__ bias, ushort* __restrict__ C,
    int K, int ldC)
{
    __shared__ ushort As[128 * 32];
    __shared__ ushort Bs[128 * 32];
    int tid = threadIdx.x;
    int m0 = blockIdx.y * 128, n0 = blockIdx.x * 128;
    int wave = tid >> 6, lane = tid & 63;
    int wm = (wave >> 1) * 64, wn = (wave & 1) * 64;
    int fr = lane & 15, q = lane >> 4;
    int sw = (q ^ ((fr >> 1) & 3)) * 8;    // swizzled k-chunk offset (ushorts)

    floatx4 acc[4][4] = {};

    for (int k0 = 0; k0 < K; k0 += 32) {
        stage128x32(A,  K, m0, k0, As, tid);
        stage128x32(Wt, K, n0, k0, Bs, tid);
        __syncthreads();
        short8 a[4], b[4];
        #pragma unroll
        for (int mi = 0; mi < 4; ++mi)
            a[mi] = *(const short8*)&As[(wm + mi * 16 + fr) * 32 + sw];
        #pragma unroll
        for (int ni = 0; ni < 4; ++ni)
            b[ni] = *(const short8*)&Bs[(wn + ni * 16 + fr) * 32 + sw];
        #pragma unroll
        for (int mi = 0; mi < 4; ++mi)
            #pragma unroll
            for (int ni = 0; ni < 4; ++ni)
                acc[mi][ni] = __builtin_amdgcn_mfma_f32_16x16x32_bf16(
                    a[mi], b[ni], acc[mi][ni], 0, 0, 0);
        __syncthreads();
    }

    #pragma unroll
    for (int ni = 0; ni < 4; ++ni) {
        int col = n0 + wn + ni * 16 + fr;
        float bsv = bias[col];
        #pragma unroll
        for (int mi = 0; mi < 4; ++mi)
            #pragma unroll
            for (int r = 0; r < 4; ++r) {
                int row = m0 + wm + mi * 16 + q * 4 + r;
                C[(size_t)row * ldC + col] = f2bf(sigmoidf_(acc[mi][ni][r] + bsv));
            }
    }
}

// ---------------------------------------------------------------------------
// MFMA dual GEMM, shared A: mode 0: tanh(z1)*sigmoid(z2); mode 1: z1*silu(z2)
// ---------------------------------------------------------------------------
__global__ __launch_bounds__(256, 2) void mfma_gemm_dual(
    const ushort* __restrict__ A, const ushort* __restrict__ W1t,
    const float* __restrict__ b1, const ushort* __restrict__ W2t,
    const float* __restrict__ b2, ushort* __restrict__ C,
    int K, int ldC, int mode)
{
    __shared__ ushort As[128 * 32];
    __shared__ ushort B1s[128 * 32];
    __shared__ ushort B2s[128 * 32];
    int tid = threadIdx.x;
    int m0 = blockIdx.y * 128, n0 = blockIdx.x * 128;
    int wave = tid >> 6, lane = tid & 63;
    int wm = (wave >> 1) * 64, wn = (wave & 1) * 64;
    int fr = lane & 15, q = lane >> 4;
    int sw = (q ^ ((fr >> 1) & 3)) * 8;

    floatx4 acc1[4][4] = {};
    floatx4 acc2[4][4] = {};

    for (int k0 = 0; k0 < K; k0 += 32) {
        stage128x32(A,   K, m0, k0, As,  tid);
        stage128x32(W1t, K, n0, k0, B1s, tid);
        stage128x32(W2t, K, n0, k0, B2s, tid);
        __syncthreads();
        short8 a[4], b[4], c[4];
        #pragma unroll
        for (int mi = 0; mi < 4; ++mi)
            a[mi] = *(const short8*)&As[(wm + mi * 16 + fr) * 32 + sw];
        #pragma unroll
        for (int ni = 0; ni < 4; ++ni) {
            b[ni] = *(const short8*)&B1s[(wn + ni * 16 + fr) * 32 + sw];
            c[ni] = *(const short8*)&B2s[(wn + ni * 16 + fr) * 32 + sw];
        }
        #pragma unroll
        for (int mi = 0; mi < 4; ++mi)
            #pragma unroll
            for (int ni = 0; ni < 4; ++ni) {
                acc1[mi][ni] = __builtin_amdgcn_mfma_f32_16x16x32_bf16(
                    a[mi], b[ni], acc1[mi][ni], 0, 0, 0);
                acc2[mi][ni] = __builtin_amdgcn_mfma_f32_16x16x32_bf16(
                    a[mi], c[ni], acc2[mi][ni], 0, 0, 0);
            }
        __syncthreads();
    }

    #pragma unroll
    for (int ni = 0; ni < 4; ++ni) {
        int col = n0 + wn + ni * 16 + fr;
        float b1v = b1[col], b2v = b2[col];
        #pragma unroll
        for (int mi = 0; mi < 4; ++mi)
            #pragma unroll
            for (int r = 0; r < 4; ++r) {
                int row = m0 + wm + mi * 16 + q * 4 + r;
                float z1 = acc1[mi][ni][r] + b1v;
                float z2 = acc2[mi][ni][r] + b2v;
                float v = (mode == 0) ? tanhf(z1) * sigmoidf_(z2)
                                      : z1 * z2 * sigmoidf_(z2);
                C[(size_t)row * ldC + col] = f2bf(v);
            }
    }
}

// ---------------------------------------------------------------------------
// MFMA residual GEMM: out_f32 = A_bf16[M,K] @ Wt[N,K]^T + bias + R (R == out)
// ---------------------------------------------------------------------------
__global__ __launch_bounds__(256, 2) void mfma_gemm_residual(
    const ushort* __restrict__ A, const ushort* __restrict__ Wt,
    const float* __restrict__ bias, float* __restrict__ C,
    int K, int ldC)
{
    __shared__ ushort As[128 * 32];
    __shared__ ushort Bs[128 * 32];
    int tid = threadIdx.x;
    int m0 = blockIdx.y * 128, n0 = blockIdx.x * 128;
    int wave = tid >> 6, lane = tid & 63;
    int wm = (wave >> 1) * 64, wn = (wave & 1) * 64;
    int fr = lane & 15, q = lane >> 4;
    int sw = (q ^ ((fr >> 1) & 3)) * 8;

    floatx4 acc[4][4] = {};

    for (int k0 = 0; k0 < K; k0 += 32) {
        stage128x32(A,  K, m0, k0, As, tid);
        stage128x32(Wt, K, n0, k0, Bs, tid);
        __syncthreads();
        short8 a[4], b[4];
        #pragma unroll
        for (int mi = 0; mi < 4; ++mi)
            a[mi] = *(const short8*)&As[(wm + mi * 16 + fr) * 32 + sw];
        #pragma unroll
        for (int ni = 0; ni < 4; ++ni)
            b[ni] = *(const short8*)&Bs[(wn + ni * 16 + fr) * 32 + sw];
        #pragma unroll
        for (int mi = 0; mi < 4; ++mi)
            #pragma unroll
            for (int ni = 0; ni < 4; ++ni)
                acc[mi][ni] = __builtin_amdgcn_mfma_f32_16x16x32_bf16(
                    a[mi], b[ni], acc[mi][ni], 0, 0, 0);
        __syncthreads();
    }

    #pragma unroll
    for (int ni = 0; ni < 4; ++ni) {
        int col = n0 + wn + ni * 16 + fr;
        float bsv = bias[col];
        #pragma unroll
        for (int mi = 0; mi < 4; ++mi)
            #pragma unroll
            for (int r = 0; r < 4; ++r) {
                int row = m0 + wm + mi * 16 + q * 4 + r;
                size_t idx = (size_t)row * ldC + col;
                C[idx] = acc[mi][ni][r] + bsv + C[idx];  // same-thread RMW
            }
    }
}

// ---------------------------------------------------------------------------
// Weight cast+transpose: W fp32 [K,N] -> Wt bf16 [N,K]
// ---------------------------------------------------------------------------
__global__ __launch_bounds__(256) void transpose_cast_kernel(
    const float* __restrict__ W, ushort* __restrict__ Wt, int K, int N)
{
    __shared__ float t[32][33];
    int lx = threadIdx.x & 31, ly = threadIdx.x >> 5;   // 32 x 8
    int n = blockIdx.x * 32 + lx;
    #pragma unroll
    for (int i = 0; i < 4; ++i) {
        int k = blockIdx.y * 32 + ly + i * 8;
        t[ly + i * 8][lx] = W[(size_t)k * N + n];
    }
    __syncthreads();
    int k2 = blockIdx.y * 32 + lx;
    #pragma unroll
    for (int i = 0; i < 4; ++i) {
        int n2 = blockIdx.x * 32 + ly + i * 8;
        Wt[(size_t)n2 * K + k2] = f2bf(t[lx][ly + i * 8]);
    }
}

// ---------------------------------------------------------------------------
// RMSNorm fp32 in -> bf16 out. One block per row.
// ---------------------------------------------------------------------------
__global__ __launch_bounds__(256) void rmsnorm_bf16_kernel(
    const float* __restrict__ x, const float* __restrict__ w,
    ushort* __restrict__ o)
{
    int row = blockIdx.x;
    int tid = threadIdx.x;
    float4 v = ((const float4*)(x + (size_t)row * Dd))[tid];
    float ss = v.x*v.x + v.y*v.y + v.z*v.z + v.w*v.w;
    #pragma unroll
    for (int off = 32; off > 0; off >>= 1) ss += __shfl_down(ss, off, 64);
    __shared__ float red[4];
    if ((tid & 63) == 0) red[tid >> 6] = ss;
    __syncthreads();
    float scale = rsqrtf((red[0] + red[1] + red[2] + red[3]) * (1.0f / Dd) + EPS);
    float4 wv = ((const float4*)w)[tid];
    us4 ov;
    ov.x = f2bf(v.x * scale * wv.x);
    ov.y = f2bf(v.y * scale * wv.y);
    ov.z = f2bf(v.z * scale * wv.z);
    ov.w = f2bf(v.w * scale * wv.w);
    *(us4*)&o[(size_t)row * Dd + tid * 4] = ov;
}

// ---------------------------------------------------------------------------
// Chunked linear recurrence over bf16 gates, fp32 accumulation
// ---------------------------------------------------------------------------
__global__ __launch_bounds__(256) void scan_pass1(
    const ushort* __restrict__ Ga, const ushort* __restrict__ Gb,
    float* __restrict__ P, float* __restrict__ Hend)
{
    int d = blockIdx.x * 256 + threadIdx.x;
    int c = blockIdx.y, b = blockIdx.z;
    size_t base = ((size_t)b * Ll + (size_t)c * CS) * Dd + d;
    float p = 1.0f, h = 0.0f;
    for (int t = 0; t < CS; ++t) {
        size_t i = base + (size_t)t * Dd;
        float aa = bf2f(Ga[i]);
        float bb = bf2f(Gb[i]);
        p *= aa;
        h = aa * h + bb;
    }
    size_t o = ((size_t)b * CH + c) * Dd + d;
    P[o] = p;
    Hend[o] = h;
}

__global__ __launch_bounds__(256) void scan_pass2(
    const float* __restrict__ P, const float* __restrict__ Hend,
    const float* __restrict__ h0, float* __restrict__ Carry)
{
    int idx = blockIdx.x * 256 + threadIdx.x;  // B*D = 4096
    int b = idx / Dd, d = idx % Dd;
    float carry = h0[d];
    for (int c = 0; c < CH; ++c) {
        size_t o = ((size_t)b * CH + c) * Dd + d;
        Carry[o] = carry;
        carry = P[o] * carry + Hend[o];
    }
}

// replay with carry + fused output gate + residual:  x1 = tanh(h)*Gog + x
__global__ __launch_bounds__(256) void scan_pass3_fused(
    const ushort* __restrict__ Ga, const ushort* __restrict__ Gb,
    const ushort* __restrict__ Gog, const float* __restrict__ Carry,
    const float* __restrict__ x, float* __restrict__ x1)
{
    int d = blockIdx.x * 256 + threadIdx.x;
    int c = blockIdx.y, b = blockIdx.z;
    size_t base = ((size_t)b * Ll + (size_t)c * CS) * Dd + d;
    float h = Carry[((size_t)b * CH + c) * Dd + d];
    for (int t = 0; t < CS; ++t) {
        size_t i = base + (size_t)t * Dd;
        float aa = bf2f(Ga[i]);
        float bb = bf2f(Gb[i]);
        h = aa * h + bb;
        x1[i] = tanhf(h) * bf2f(Gog[i]) + x[i];
    }
}

// ---------------------------------------------------------------------------
// Launch. Workspace (195 MB total, matches round-2 proven footprint):
//   [0,32)    MB: bf16 weights (4 gate 2MB each, fc 8, fc_act 8, out 8)
//   [32,64)   MB: xnb bf16 [M,1024]  (xn then xn2)
//   [64,192)  MB: Ga/Gb/Gog bf16 (32MB each) -> later hff bf16 [M,4096]
//   [192,195) MB: P, Hend, Carry fp32 (1MB each)
// d_out doubles as x1 then final out.
// ---------------------------------------------------------------------------
extern "C" void kernel_launch(void* const* d_in, const int* in_sizes, int n_in,
                              void* d_out, int out_size, void* d_ws, size_t ws_size,
                              hipStream_t stream)
{
    const float* x        = (const float*)d_in[0];
    const float* w_forget = (const float*)d_in[1];
    const float* b_forget = (const float*)d_in[2];
    const float* w_input  = (const float*)d_in[3];
    const float* b_input  = (const float*)d_in[4];
    const float* w_igate  = (const float*)d_in[5];
    const float* b_igate  = (const float*)d_in[6];
    const float* w_ogate  = (const float*)d_in[7];
    const float* b_ogate  = (const float*)d_in[8];
    const float* h0       = (const float*)d_in[9];
    const float* norm1_w  = (const float*)d_in[10];
    const float* norm2_w  = (const float*)d_in[11];
    const float* w_fc     = (const float*)d_in[12];
    const float* b_fc     = (const float*)d_in[13];
    const float* w_fc_act = (const float*)d_in[14];
    const float* b_fc_act = (const float*)d_in[15];
    const float* w_out    = (const float*)d_in[16];
    const float* b_out    = (const float*)d_in[17];
    float* out = (float*)d_out;   // x1, then final out

    char* ws = (char*)d_ws;
    const size_t MB = 1ull << 20;
    ushort* wtF   = (ushort*)(ws + 0 * MB);
    ushort* wtI   = (ushort*)(ws + 2 * MB);
    ushort* wtG   = (ushort*)(ws + 4 * MB);
    ushort* wtO   = (ushort*)(ws + 6 * MB);
    ushort* wtFC  = (ushort*)(ws + 8 * MB);
    ushort* wtFCA = (ushort*)(ws + 16 * MB);
    ushort* wtOUT = (ushort*)(ws + 24 * MB);
    ushort* xnb   = (ushort*)(ws + 32 * MB);
    ushort* Ga    = (ushort*)(ws + 64 * MB);
    ushort* Gb    = (ushort*)(ws + 96 * MB);
    ushort* Gog   = (ushort*)(ws + 128 * MB);
    ushort* hff   = (ushort*)(ws + 64 * MB);   // [M,4096] bf16, reuses gate region
    float*  P     = (float*)(ws + 192 * MB);
    float*  Hend  = (float*)(ws + 193 * MB);
    float*  Carry = (float*)(ws + 194 * MB);

    // 0) weights -> bf16 [N,K]
    transpose_cast_kernel<<<dim3(Dd/32, Dd/32), 256, 0, stream>>>(w_forget, wtF,  Dd, Dd);
    transpose_cast_kernel<<<dim3(Dd/32, Dd/32), 256, 0, stream>>>(w_input,  wtI,  Dd, Dd);
    transpose_cast_kernel<<<dim3(Dd/32, Dd/32), 256, 0, stream>>>(w_igate,  wtG,  Dd, Dd);
    transpose_cast_kernel<<<dim3(Dd/32, Dd/32), 256, 0, stream>>>(w_ogate,  wtO,  Dd, Dd);
    transpose_cast_kernel<<<dim3(DFF/32, Dd/32), 256, 0, stream>>>(w_fc,     wtFC,  Dd, DFF);
    transpose_cast_kernel<<<dim3(DFF/32, Dd/32), 256, 0, stream>>>(w_fc_act, wtFCA, Dd, DFF);
    transpose_cast_kernel<<<dim3(Dd/32, DFF/32), 256, 0, stream>>>(w_out,    wtOUT, DFF, Dd);

    // 1) xn = rmsnorm(x) -> bf16
    rmsnorm_bf16_kernel<<<Mm, 256, 0, stream>>>(x, norm1_w, xnb);

    // 2) gates (bf16 MFMA GEMMs)
    dim3 gg(Dd / 128, Mm / 128);
    mfma_gemm_sigmoid<<<gg, 256, 0, stream>>>(xnb, wtF, b_forget, Ga, Dd, Dd);
    mfma_gemm_dual<<<gg, 256, 0, stream>>>(xnb, wtI, b_input, wtG, b_igate,
                                           Gb, Dd, Dd, /*mode=*/0);
    mfma_gemm_sigmoid<<<gg, 256, 0, stream>>>(xnb, wtO, b_ogate, Gog, Dd, Dd);

    // 3) chunked scan + fused ogate/residual -> x1 (= d_out)
    dim3 sg(Dd / 256, CH, Bb);
    scan_pass1<<<sg, 256, 0, stream>>>(Ga, Gb, P, Hend);
    scan_pass2<<<(Bb * Dd) / 256, 256, 0, stream>>>(P, Hend, h0, Carry);
    scan_pass3_fused<<<sg, 256, 0, stream>>>(Ga, Gb, Gog, Carry, x, out);

    // 4) xn2 = rmsnorm(x1) -> bf16 (gates now dead; hff region free)
    rmsnorm_bf16_kernel<<<Mm, 256, 0, stream>>>(out, norm2_w, xnb);

    // 5) hff = (xn2@w_fc + b) * silu(xn2@w_fc_act + b)  -> bf16 [M,4096]
    dim3 gf(DFF / 128, Mm / 128);
    mfma_gemm_dual<<<gf, 256, 0, stream>>>(xnb, wtFC, b_fc, wtFCA, b_fc_act,
                                           hff, Dd, DFF, /*mode=*/1);

    // 6) out = hff @ w_out + b_out + x1   (in-place on d_out)
    dim3 go(Dd / 128, Mm / 128);
    mfma_gemm_residual<<<go, 256, 0, stream>>>(hff, wtOUT, b_out, out, DFF, Dd);
}

// Round 4
// 971.959 us; speedup vs baseline: 7.2011x; 1.0517x over previous
//
#include <hip/hip_runtime.h>
#include <math.h>
#include <stdint.h>

// Problem dims (fixed by reference)
static constexpr int Bb  = 4;
static constexpr int Ll  = 4096;
static constexpr int Dd  = 1024;
static constexpr int DFF = 4096;
static constexpr int Mm  = Bb * Ll;     // 16384 rows
static constexpr int CH  = 64;          // scan chunks
static constexpr int CS  = Ll / CH;     // 64 steps per chunk
static constexpr float EPS = 1e-6f;

typedef __attribute__((ext_vector_type(8))) short short8;     // 8 bf16 (4 VGPRs)
typedef __attribute__((ext_vector_type(4))) float floatx4;    // MFMA C/D
typedef __attribute__((ext_vector_type(4))) unsigned short us4;

__device__ __forceinline__ float sigmoidf_(float v) { return 1.0f / (1.0f + __expf(-v)); }
// safe at +-inf: 2*sigmoid(2x)-1
__device__ __forceinline__ float fast_tanh(float x) {
    return 2.0f / (1.0f + __expf(-2.0f * x)) - 1.0f;
}
__device__ __forceinline__ ushort f2bf(float f) {
    union { float f; uint32_t u; } v; v.f = f;
    return (ushort)((v.u + 0x7FFFu + ((v.u >> 16) & 1u)) >> 16);   // RNE
}
__device__ __forceinline__ float bf2f(ushort h) {
    union { uint32_t u; float f; } v; v.u = (uint32_t)h << 16; return v.f;
}

// async global->LDS, 16 bytes per lane (wave-uniform base + lane*16 layout)
__device__ __forceinline__ void gload16(const ushort* g, ushort* l) {
    __builtin_amdgcn_global_load_lds(
        (const __attribute__((address_space(1))) uint32_t*)g,
        (__attribute__((address_space(3))) uint32_t*)l, 16, 0, 0);
}

// ---------------------------------------------------------------------------
// Stage a 128x32 bf16 tile into LDS, layout [m][32k] with 16B-chunk XOR
// swizzle: lds chunk (m*4 + slot) holds global k-block (slot ^ ((m>>1)&3)).
// 2-way LDS bank aliasing on fragment ds_read_b128 = free (m136).
// ---------------------------------------------------------------------------
__device__ __forceinline__ void stage128x32(const ushort* __restrict__ src, int ld,
                                            int r0, int k0, ushort* lds, int tid)
{
    #pragma unroll
    for (int h = 0; h < 2; ++h) {
        int c  = tid + h * 256;            // chunk 0..511
        int m  = c >> 2;
        int kb = (c & 3) ^ ((m >> 1) & 3);
        gload16(src + (size_t)(r0 + m) * ld + k0 + kb * 8, lds + c * 8);
    }
}

// ---------------------------------------------------------------------------
// Fused QuasiLSTM gate GEMM (dual, shared A), N = 2048:
//   W1t rows [0,1024) = w_input^T,  [1024,2048) = w_forget^T
//   W2t rows [0,1024) = w_igate^T,  [1024,2048) = w_ogate^T
// col <  1024:  Gb  = tanh(z1) * sigmoid(z2)
// col >= 1024:  Ga  = sigmoid(z1);  Gog = sigmoid(z2)
// ---------------------------------------------------------------------------
__global__ __launch_bounds__(256, 2) void mfma_gemm_gates(
    const ushort* __restrict__ A, const ushort* __restrict__ W1t,
    const ushort* __restrict__ W2t,
    const float* __restrict__ b_input, const float* __restrict__ b_forget,
    const float* __restrict__ b_igate, const float* __restrict__ b_ogate,
    ushort* __restrict__ Ga, ushort* __restrict__ Gb, ushort* __restrict__ Gog,
    int K)
{
    __shared__ ushort As[128 * 32];
    __shared__ ushort B1s[128 * 32];
    __shared__ ushort B2s[128 * 32];
    int tid = threadIdx.x;
    int m0 = blockIdx.y * 128, n0 = blockIdx.x * 128;
    int wave = tid >> 6, lane = tid & 63;
    int wm = (wave >> 1) * 64, wn = (wave & 1) * 64;
    int fr = lane & 15, q = lane >> 4;
    int sw = (q ^ ((fr >> 1) & 3)) * 8;

    floatx4 acc1[4][4] = {};
    floatx4 acc2[4][4] = {};

    for (int k0 = 0; k0 < K; k0 += 32) {
        stage128x32(A,   K, m0, k0, As,  tid);
        stage128x32(W1t, K, n0, k0, B1s, tid);
        stage128x32(W2t, K, n0, k0, B2s, tid);
        __syncthreads();
        short8 a[4], b[4], c[4];
        #pragma unroll
        for (int mi = 0; mi < 4; ++mi)
            a[mi] = *(const short8*)&As[(wm + mi * 16 + fr) * 32 + sw];
        #pragma unroll
        for (int ni = 0; ni < 4; ++ni) {
            b[ni] = *(const short8*)&B1s[(wn + ni * 16 + fr) * 32 + sw];
            c[ni] = *(const short8*)&B2s[(wn + ni * 16 + fr) * 32 + sw];
        }
        #pragma unroll
        for (int mi = 0; mi < 4; ++mi)
            #pragma unroll
            for (int ni = 0; ni < 4; ++ni) {
                acc1[mi][ni] = __builtin_amdgcn_mfma_f32_16x16x32_bf16(
                    a[mi], b[ni], acc1[mi][ni], 0, 0, 0);
                acc2[mi][ni] = __builtin_amdgcn_mfma_f32_16x16x32_bf16(
                    a[mi], c[ni], acc2[mi][ni], 0, 0, 0);
            }
        __syncthreads();
    }

    #pragma unroll
    for (int ni = 0; ni < 4; ++ni) {
        int col = n0 + wn + ni * 16 + fr;          // [0,2048)
        if (col < 1024) {
            float b1v = b_input[col], b2v = b_igate[col];
            #pragma unroll
            for (int mi = 0; mi < 4; ++mi)
                #pragma unroll
                for (int r = 0; r < 4; ++r) {
                    int row = m0 + wm + mi * 16 + q * 4 + r;
                    float z1 = acc1[mi][ni][r] + b1v;
                    float z2 = acc2[mi][ni][r] + b2v;
                    Gb[(size_t)row * Dd + col] = f2bf(fast_tanh(z1) * sigmoidf_(z2));
                }
        } else {
            int c2 = col - 1024;
            float b1v = b_forget[c2], b2v = b_ogate[c2];
            #pragma unroll
            for (int mi = 0; mi < 4; ++mi)
                #pragma unroll
                for (int r = 0; r < 4; ++r) {
                    int row = m0 + wm + mi * 16 + q * 4 + r;
                    float z1 = acc1[mi][ni][r] + b1v;
                    float z2 = acc2[mi][ni][r] + b2v;
                    Ga[(size_t)row * Dd + c2]  = f2bf(sigmoidf_(z1));
                    Gog[(size_t)row * Dd + c2] = f2bf(sigmoidf_(z2));
                }
        }
    }
}

// ---------------------------------------------------------------------------
// MFMA dual GEMM for SwiGLU: C = (A@W1+b1) * silu(A@W2+b2), bf16 out
// ---------------------------------------------------------------------------
__global__ __launch_bounds__(256, 2) void mfma_gemm_swiglu(
    const ushort* __restrict__ A, const ushort* __restrict__ W1t,
    const float* __restrict__ b1, const ushort* __restrict__ W2t,
    const float* __restrict__ b2, ushort* __restrict__ C,
    int K, int ldC)
{
    __shared__ ushort As[128 * 32];
    __shared__ ushort B1s[128 * 32];
    __shared__ ushort B2s[128 * 32];
    int tid = threadIdx.x;
    int m0 = blockIdx.y * 128, n0 = blockIdx.x * 128;
    int wave = tid >> 6, lane = tid & 63;
    int wm = (wave >> 1) * 64, wn = (wave & 1) * 64;
    int fr = lane & 15, q = lane >> 4;
    int sw = (q ^ ((fr >> 1) & 3)) * 8;

    floatx4 acc1[4][4] = {};
    floatx4 acc2[4][4] = {};

    for (int k0 = 0; k0 < K; k0 += 32) {
        stage128x32(A,   K, m0, k0, As,  tid);
        stage128x32(W1t, K, n0, k0, B1s, tid);
        stage128x32(W2t, K, n0, k0, B2s, tid);
        __syncthreads();
        short8 a[4], b[4], c[4];
        #pragma unroll
        for (int mi = 0; mi < 4; ++mi)
            a[mi] = *(const short8*)&As[(wm + mi * 16 + fr) * 32 + sw];
        #pragma unroll
        for (int ni = 0; ni < 4; ++ni) {
            b[ni] = *(const short8*)&B1s[(wn + ni * 16 + fr) * 32 + sw];
            c[ni] = *(const short8*)&B2s[(wn + ni * 16 + fr) * 32 + sw];
        }
        #pragma unroll
        for (int mi = 0; mi < 4; ++mi)
            #pragma unroll
            for (int ni = 0; ni < 4; ++ni) {
                acc1[mi][ni] = __builtin_amdgcn_mfma_f32_16x16x32_bf16(
                    a[mi], b[ni], acc1[mi][ni], 0, 0, 0);
                acc2[mi][ni] = __builtin_amdgcn_mfma_f32_16x16x32_bf16(
                    a[mi], c[ni], acc2[mi][ni], 0, 0, 0);
            }
        __syncthreads();
    }

    #pragma unroll
    for (int ni = 0; ni < 4; ++ni) {
        int col = n0 + wn + ni * 16 + fr;
        float b1v = b1[col], b2v = b2[col];
        #pragma unroll
        for (int mi = 0; mi < 4; ++mi)
            #pragma unroll
            for (int r = 0; r < 4; ++r) {
                int row = m0 + wm + mi * 16 + q * 4 + r;
                float z1 = acc1[mi][ni][r] + b1v;
                float z2 = acc2[mi][ni][r] + b2v;
                C[(size_t)row * ldC + col] = f2bf(z1 * z2 * sigmoidf_(z2));
            }
    }
}

// ---------------------------------------------------------------------------
// MFMA residual GEMM: out_f32 = A_bf16[M,K] @ Wt[N,K]^T + bias + R (R == out)
// ---------------------------------------------------------------------------
__global__ __launch_bounds__(256, 2) void mfma_gemm_residual(
    const ushort* __restrict__ A, const ushort* __restrict__ Wt,
    const float* __restrict__ bias, float* __restrict__ C,
    int K, int ldC)
{
    __shared__ ushort As[128 * 32];
    __shared__ ushort Bs[128 * 32];
    int tid = threadIdx.x;
    int m0 = blockIdx.y * 128, n0 = blockIdx.x * 128;
    int wave = tid >> 6, lane = tid & 63;
    int wm = (wave >> 1) * 64, wn = (wave & 1) * 64;
    int fr = lane & 15, q = lane >> 4;
    int sw = (q ^ ((fr >> 1) & 3)) * 8;

    floatx4 acc[4][4] = {};

    for (int k0 = 0; k0 < K; k0 += 32) {
        stage128x32(A,  K, m0, k0, As, tid);
        stage128x32(Wt, K, n0, k0, Bs, tid);
        __syncthreads();
        short8 a[4], b[4];
        #pragma unroll
        for (int mi = 0; mi < 4; ++mi)
            a[mi] = *(const short8*)&As[(wm + mi * 16 + fr) * 32 + sw];
        #pragma unroll
        for (int ni = 0; ni < 4; ++ni)
            b[ni] = *(const short8*)&Bs[(wn + ni * 16 + fr) * 32 + sw];
        #pragma unroll
        for (int mi = 0; mi < 4; ++mi)
            #pragma unroll
            for (int ni = 0; ni < 4; ++ni)
                acc[mi][ni] = __builtin_amdgcn_mfma_f32_16x16x32_bf16(
                    a[mi], b[ni], acc[mi][ni], 0, 0, 0);
        __syncthreads();
    }

    #pragma unroll
    for (int ni = 0; ni < 4; ++ni) {
        int col = n0 + wn + ni * 16 + fr;
        float bsv = bias[col];
        #pragma unroll
        for (int mi = 0; mi < 4; ++mi)
            #pragma unroll
            for (int r = 0; r < 4; ++r) {
                int row = m0 + wm + mi * 16 + q * 4 + r;
                size_t idx = (size_t)row * ldC + col;
                C[idx] = acc[mi][ni][r] + bsv + C[idx];  // same-thread RMW
            }
    }
}

// ---------------------------------------------------------------------------
// Weight cast+transpose: W fp32 [K,N] -> Wt bf16 [N,K]
// ---------------------------------------------------------------------------
__global__ __launch_bounds__(256) void transpose_cast_kernel(
    const float* __restrict__ W, ushort* __restrict__ Wt, int K, int N)
{
    __shared__ float t[32][33];
    int lx = threadIdx.x & 31, ly = threadIdx.x >> 5;   // 32 x 8
    int n = blockIdx.x * 32 + lx;
    #pragma unroll
    for (int i = 0; i < 4; ++i) {
        int k = blockIdx.y * 32 + ly + i * 8;
        t[ly + i * 8][lx] = W[(size_t)k * N + n];
    }
    __syncthreads();
    int k2 = blockIdx.y * 32 + lx;
    #pragma unroll
    for (int i = 0; i < 4; ++i) {
        int n2 = blockIdx.x * 32 + ly + i * 8;
        Wt[(size_t)n2 * K + k2] = f2bf(t[lx][ly + i * 8]);
    }
}

// Batched version for the four 1024x1024 gate weights (grid.z picks source).
// z=0: w_input -> W1t[0:1024)   z=1: w_forget -> W1t[1024:2048)
// z=2: w_igate -> W2t[0:1024)   z=3: w_ogate -> W2t[1024:2048)
__global__ __launch_bounds__(256) void transpose_cast_gates(
    const float* __restrict__ w_i, const float* __restrict__ w_f,
    const float* __restrict__ w_g, const float* __restrict__ w_o,
    ushort* __restrict__ W1t, ushort* __restrict__ W2t)
{
    int z = blockIdx.z;
    const float* W = (z == 0) ? w_i : (z == 1) ? w_f : (z == 2) ? w_g : w_o;
    ushort* Wt = (z == 0) ? W1t : (z == 1) ? W1t + (size_t)1024 * Dd
               : (z == 2) ? W2t : W2t + (size_t)1024 * Dd;
    __shared__ float t[32][33];
    int lx = threadIdx.x & 31, ly = threadIdx.x >> 5;
    int n = blockIdx.x * 32 + lx;
    #pragma unroll
    for (int i = 0; i < 4; ++i) {
        int k = blockIdx.y * 32 + ly + i * 8;
        t[ly + i * 8][lx] = W[(size_t)k * Dd + n];
    }
    __syncthreads();
    int k2 = blockIdx.y * 32 + lx;
    #pragma unroll
    for (int i = 0; i < 4; ++i) {
        int n2 = blockIdx.x * 32 + ly + i * 8;
        Wt[(size_t)n2 * Dd + k2] = f2bf(t[lx][ly + i * 8]);
    }
}

// ---------------------------------------------------------------------------
// RMSNorm fp32 in -> bf16 out. One block per row.
// ---------------------------------------------------------------------------
__global__ __launch_bounds__(256) void rmsnorm_bf16_kernel(
    const float* __restrict__ x, const float* __restrict__ w,
    ushort* __restrict__ o)
{
    int row = blockIdx.x;
    int tid = threadIdx.x;
    float4 v = ((const float4*)(x + (size_t)row * Dd))[tid];
    float ss = v.x*v.x + v.y*v.y + v.z*v.z + v.w*v.w;
    #pragma unroll
    for (int off = 32; off > 0; off >>= 1) ss += __shfl_down(ss, off, 64);
    __shared__ float red[4];
    if ((tid & 63) == 0) red[tid >> 6] = ss;
    __syncthreads();
    float scale = rsqrtf((red[0] + red[1] + red[2] + red[3]) * (1.0f / Dd) + EPS);
    float4 wv = ((const float4*)w)[tid];
    us4 ov;
    ov.x = f2bf(v.x * scale * wv.x);
    ov.y = f2bf(v.y * scale * wv.y);
    ov.z = f2bf(v.z * scale * wv.z);
    ov.w = f2bf(v.w * scale * wv.w);
    *(us4*)&o[(size_t)row * Dd + tid * 4] = ov;
}

// ---------------------------------------------------------------------------
// Chunked linear recurrence, 4 channels/thread (ushort4 loads)
// Block = one (chunk, batch); 256 threads cover all 1024 channels.
// ---------------------------------------------------------------------------
__global__ __launch_bounds__(256) void scan_pass1(
    const ushort* __restrict__ Ga, const ushort* __restrict__ Gb,
    float* __restrict__ P, float* __restrict__ Hend)
{
    int tid = threadIdx.x;
    int c = blockIdx.x, b = blockIdx.y;
    size_t base = ((size_t)b * Ll + (size_t)c * CS) * Dd + tid * 4;
    float p[4] = {1.f, 1.f, 1.f, 1.f};
    float h[4] = {};
    #pragma unroll 4
    for (int t = 0; t < CS; ++t) {
        us4 av = *(const us4*)&Ga[base + (size_t)t * Dd];
        us4 bv = *(const us4*)&Gb[base + (size_t)t * Dd];
        #pragma unroll
        for (int j = 0; j < 4; ++j) {
            float aa = bf2f(av[j]);
            float bb = bf2f(bv[j]);
            p[j] *= aa;
            h[j] = aa * h[j] + bb;
        }
    }
    size_t o = ((size_t)b * CH + c) * Dd + tid * 4;
    *(float4*)&P[o]    = make_float4(p[0], p[1], p[2], p[3]);
    *(float4*)&Hend[o] = make_float4(h[0], h[1], h[2], h[3]);
}

__global__ __launch_bounds__(256) void scan_pass2(
    const float* __restrict__ P, const float* __restrict__ Hend,
    const float* __restrict__ h0, float* __restrict__ Carry)
{
    int idx = blockIdx.x * 256 + threadIdx.x;  // B*D = 4096
    int b = idx / Dd, d = idx % Dd;
    float carry = h0[d];
    for (int c = 0; c < CH; ++c) {
        size_t o = ((size_t)b * CH + c) * Dd + d;
        Carry[o] = carry;
        carry = P[o] * carry + Hend[o];
    }
}

// Replay with carry + fused ogate/residual + fused RMSNorm2:
//   x1 = tanh(h)*Gog + x            (fp32, to d_out)
//   xnb = rmsnorm(x1, norm2_w)      (bf16, feeds FFN)
// Block = (chunk, batch), 256 threads x 4 channels = full 1024-wide row per t.
// ---------------------------------------------------------------------------
__global__ __launch_bounds__(256) void scan_pass3_norm(
    const ushort* __restrict__ Ga, const ushort* __restrict__ Gb,
    const ushort* __restrict__ Gog, const float* __restrict__ Carry,
    const float* __restrict__ x, const float* __restrict__ norm2w,
    float* __restrict__ x1, ushort* __restrict__ xnb)
{
    int tid = threadIdx.x;
    int c = blockIdx.x, b = blockIdx.y;
    size_t base = ((size_t)b * Ll + (size_t)c * CS) * Dd + tid * 4;
    float4 h4 = *(const float4*)&Carry[((size_t)b * CH + c) * Dd + tid * 4];
    float h[4] = {h4.x, h4.y, h4.z, h4.w};
    float4 w4 = ((const float4*)norm2w)[tid];
    float wv[4] = {w4.x, w4.y, w4.z, w4.w};
    __shared__ float red[4];

    for (int t = 0; t < CS; ++t) {
        size_t i = base + (size_t)t * Dd;
        us4 av = *(const us4*)&Ga[i];
        us4 bv = *(const us4*)&Gb[i];
        us4 gv = *(const us4*)&Gog[i];
        float4 xv = *(const float4*)&x[i];
        float xs[4] = {xv.x, xv.y, xv.z, xv.w};
        float v[4];
        #pragma unroll
        for (int j = 0; j < 4; ++j) {
            float aa = bf2f(av[j]);
            float bb = bf2f(bv[j]);
            h[j] = aa * h[j] + bb;
            v[j] = fast_tanh(h[j]) * bf2f(gv[j]) + xs[j];
        }
        *(float4*)&x1[i] = make_float4(v[0], v[1], v[2], v[3]);
        // block RMS reduction over the 1024-wide row
        float ss = v[0]*v[0] + v[1]*v[1] + v[2]*v[2] + v[3]*v[3];
        #pragma unroll
        for (int off = 32; off > 0; off >>= 1) ss += __shfl_down(ss, off, 64);
        if ((tid & 63) == 0) red[tid >> 6] = ss;
        __syncthreads();
        float scale = rsqrtf((red[0] + red[1] + red[2] + red[3]) * (1.0f / Dd) + EPS);
        us4 ov;
        #pragma unroll
        for (int j = 0; j < 4; ++j) ov[j] = f2bf(v[j] * scale * wv[j]);
        *(us4*)&xnb[i] = ov;
        __syncthreads();   // protect red[] before next t overwrites
    }
}

// ---------------------------------------------------------------------------
// Launch. Workspace (195 MB):
//   [0,4)   MB: W1t gates bf16 [2048,1024]   (input | forget)
//   [4,8)   MB: W2t gates bf16 [2048,1024]   (igate | ogate)
//   [8,16)  MB: wtFC   [16,24) MB: wtFCA   [24,32) MB: wtOUT
//   [32,64) MB: xnb bf16 [M,1024]
//   [64,192)MB: Ga/Gb/Gog bf16 (32MB each) -> later hff bf16 [M,4096]
//   [192,195)MB: P, Hend, Carry fp32
// d_out doubles as x1 then final out.
// ---------------------------------------------------------------------------
extern "C" void kernel_launch(void* const* d_in, const int* in_sizes, int n_in,
                              void* d_out, int out_size, void* d_ws, size_t ws_size,
                              hipStream_t stream)
{
    const float* x        = (const float*)d_in[0];
    const float* w_forget = (const float*)d_in[1];
    const float* b_forget = (const float*)d_in[2];
    const float* w_input  = (const float*)d_in[3];
    const float* b_input  = (const float*)d_in[4];
    const float* w_igate  = (const float*)d_in[5];
    const float* b_igate  = (const float*)d_in[6];
    const float* w_ogate  = (const float*)d_in[7];
    const float* b_ogate  = (const float*)d_in[8];
    const float* h0       = (const float*)d_in[9];
    const float* norm1_w  = (const float*)d_in[10];
    const float* norm2_w  = (const float*)d_in[11];
    const float* w_fc     = (const float*)d_in[12];
    const float* b_fc     = (const float*)d_in[13];
    const float* w_fc_act = (const float*)d_in[14];
    const float* b_fc_act = (const float*)d_in[15];
    const float* w_out    = (const float*)d_in[16];
    const float* b_out    = (const float*)d_in[17];
    float* out = (float*)d_out;   // x1, then final out

    char* ws = (char*)d_ws;
    const size_t MB = 1ull << 20;
    ushort* wtG1  = (ushort*)(ws + 0 * MB);
    ushort* wtG2  = (ushort*)(ws + 4 * MB);
    ushort* wtFC  = (ushort*)(ws + 8 * MB);
    ushort* wtFCA = (ushort*)(ws + 16 * MB);
    ushort* wtOUT = (ushort*)(ws + 24 * MB);
    ushort* xnb   = (ushort*)(ws + 32 * MB);
    ushort* Ga    = (ushort*)(ws + 64 * MB);
    ushort* Gb    = (ushort*)(ws + 96 * MB);
    ushort* Gog   = (ushort*)(ws + 128 * MB);
    ushort* hff   = (ushort*)(ws + 64 * MB);   // [M,4096] bf16, reuses gate region
    float*  P     = (float*)(ws + 192 * MB);
    float*  Hend  = (float*)(ws + 193 * MB);
    float*  Carry = (float*)(ws + 194 * MB);

    // 0) weights -> bf16 [N,K]
    transpose_cast_gates<<<dim3(32, 32, 4), 256, 0, stream>>>(
        w_input, w_forget, w_igate, w_ogate, wtG1, wtG2);
    transpose_cast_kernel<<<dim3(DFF/32, Dd/32), 256, 0, stream>>>(w_fc,     wtFC,  Dd, DFF);
    transpose_cast_kernel<<<dim3(DFF/32, Dd/32), 256, 0, stream>>>(w_fc_act, wtFCA, Dd, DFF);
    transpose_cast_kernel<<<dim3(Dd/32, DFF/32), 256, 0, stream>>>(w_out,    wtOUT, DFF, Dd);

    // 1) xn = rmsnorm(x) -> bf16
    rmsnorm_bf16_kernel<<<Mm, 256, 0, stream>>>(x, norm1_w, xnb);

    // 2) all four gates in one dual-GEMM (N = 2048)
    dim3 gg(2048 / 128, Mm / 128);
    mfma_gemm_gates<<<gg, 256, 0, stream>>>(xnb, wtG1, wtG2,
                                            b_input, b_forget, b_igate, b_ogate,
                                            Ga, Gb, Gog, Dd);

    // 3) chunked scan + fused ogate/residual + fused rmsnorm2
    dim3 sg(CH, Bb);
    scan_pass1<<<sg, 256, 0, stream>>>(Ga, Gb, P, Hend);
    scan_pass2<<<(Bb * Dd) / 256, 256, 0, stream>>>(P, Hend, h0, Carry);
    scan_pass3_norm<<<sg, 256, 0, stream>>>(Ga, Gb, Gog, Carry, x, norm2_w,
                                            out, xnb);

    // 4) hff = (xn2@w_fc + b) * silu(xn2@w_fc_act + b)  -> bf16 [M,4096]
    dim3 gf(DFF / 128, Mm / 128);
    mfma_gemm_swiglu<<<gf, 256, 0, stream>>>(xnb, wtFC, b_fc, wtFCA, b_fc_act,
                                             hff, Dd, DFF);

    // 5) out = hff @ w_out + b_out + x1   (in-place on d_out)
    dim3 go(Dd / 128, Mm / 128);
    mfma_gemm_residual<<<go, 256, 0, stream>>>(hff, wtOUT, b_out, out, DFF, Dd);
}